// Round 1
// baseline (104.253 us; speedup 1.0000x reference)
//
#include <hip/hip_runtime.h>
#include <math.h>

#define N_LAYERS 5
#define N_WIRES 4
#define NGATES (N_LAYERS * N_WIRES)

// One thread per sample. State = 16 complex amps in registers.
// Shared (weight-derived) gates precomputed per-block into LDS.
__global__ __launch_bounds__(256) void qlayer_kernel(
    const float* __restrict__ x,
    const float* __restrict__ w,
    float* __restrict__ out)
{
    __shared__ float g[NGATES][8];  // m00r, m00i(=0, unused), m01r, m01i, m10r, m10i, m11r, m11i
    const int t = threadIdx.x;
    if (t < NGATES) {
        float th = w[t * 3 + 0], ph = w[t * 3 + 1], la = w[t * 3 + 2];
        float ct, st, cl, sl, cp, sp, cpl, spl;
        __sincosf(th * 0.5f, &st, &ct);
        __sincosf(la, &sl, &cl);
        __sincosf(ph, &sp, &cp);
        __sincosf(ph + la, &spl, &cpl);
        g[t][0] = ct;        // m00 (real)
        g[t][1] = 0.0f;
        g[t][2] = -cl * st;  // m01 = -e^{i la} sin
        g[t][3] = -sl * st;
        g[t][4] = cp * st;   // m10 = e^{i ph} sin
        g[t][5] = sp * st;
        g[t][6] = cpl * ct;  // m11 = e^{i(ph+la)} cos
        g[t][7] = spl * ct;
    }
    __syncthreads();

    const int b = blockIdx.x * 256 + t;
    const float4 xv = ((const float4*)x)[b];
    const float xs[4] = {xv.x, xv.y, xv.z, xv.w};

    // --- Encoding: U3(x,x,x)|0> = [cos(x/2), e^{ix} sin(x/2)] per wire ---
    float vr[4][2], vi[4][2];
#pragma unroll
    for (int i = 0; i < 4; i++) {
        float ct, st, cx, sx;
        __sincosf(xs[i] * 0.5f, &st, &ct);
        __sincosf(xs[i], &sx, &cx);
        vr[i][0] = ct;      vi[i][0] = 0.0f;
        vr[i][1] = cx * st; vi[i][1] = sx * st;
    }

    // --- Tensor product -> 16 amplitudes. Flat idx: wire0 = bit3 (MSB) ---
    float w01r[4], w01i[4], w23r[4], w23i[4];
#pragma unroll
    for (int a = 0; a < 2; a++) {
#pragma unroll
        for (int c = 0; c < 2; c++) {
            w01r[a * 2 + c] = vr[0][a] * vr[1][c] - vi[0][a] * vi[1][c];
            w01i[a * 2 + c] = vr[0][a] * vi[1][c] + vi[0][a] * vr[1][c];
            w23r[a * 2 + c] = vr[2][a] * vr[3][c] - vi[2][a] * vi[3][c];
            w23i[a * 2 + c] = vr[2][a] * vi[3][c] + vi[2][a] * vr[3][c];
        }
    }
    float ar[16], ai[16];
#pragma unroll
    for (int hi = 0; hi < 4; hi++) {
#pragma unroll
        for (int lo = 0; lo < 4; lo++) {
            ar[hi * 4 + lo] = w01r[hi] * w23r[lo] - w01i[hi] * w23i[lo];
            ai[hi * 4 + lo] = w01r[hi] * w23i[lo] + w01i[hi] * w23r[lo];
        }
    }

    // --- Variational layers ---
    const int ringc[4] = {0, 1, 2, 3};
    const int ringt[4] = {1, 2, 3, 0};
#pragma unroll
    for (int l = 0; l < N_LAYERS; l++) {
#pragma unroll
        for (int wi = 0; wi < 4; wi++) {
            const float* gm = g[l * 4 + wi];
            const float m00r = gm[0];
            const float m01r = gm[2], m01i = gm[3];
            const float m10r = gm[4], m10i = gm[5];
            const float m11r = gm[6], m11i = gm[7];
            const int stride = 8 >> wi;
#pragma unroll
            for (int base = 0; base < 16; base++) {
                if (base & stride) continue;  // compile-time skip
                const int i1 = base + stride;
                const float s0r = ar[base], s0i = ai[base];
                const float s1r = ar[i1],   s1i = ai[i1];
                // m00 is purely real: 3 FMAs instead of 4 on row 0
                ar[base] = m00r * s0r + m01r * s1r - m01i * s1i;
                ai[base] = m00r * s0i + m01r * s1i + m01i * s1r;
                ar[i1]   = m10r * s0r - m10i * s0i + m11r * s1r - m11i * s1i;
                ai[i1]   = m10r * s0i + m10i * s0r + m11r * s1i + m11i * s1r;
            }
        }
        // Ring CNOTs: register renames (free after unroll)
#pragma unroll
        for (int e = 0; e < 4; e++) {
            const int cm = 8 >> ringc[e];
            const int tm = 8 >> ringt[e];
#pragma unroll
            for (int idx = 0; idx < 16; idx++) {
                if ((idx & cm) && !(idx & tm)) {
                    const int j = idx | tm;
                    float tr = ar[idx]; ar[idx] = ar[j]; ar[j] = tr;
                    float ti = ai[idx]; ai[idx] = ai[j]; ai[j] = ti;
                }
            }
        }
    }

    // --- Probabilities and <Z_i> ---
    float p[16];
#pragma unroll
    for (int i = 0; i < 16; i++) p[i] = ar[i] * ar[i] + ai[i] * ai[i];

    float z[4];
#pragma unroll
    for (int wi = 0; wi < 4; wi++) {
        const int m = 8 >> wi;
        float s = 0.0f;
#pragma unroll
        for (int i = 0; i < 16; i++) s += (i & m) ? -p[i] : p[i];
        z[wi] = s;
    }
    ((float4*)out)[b] = make_float4(z[0], z[1], z[2], z[3]);
}

extern "C" void kernel_launch(void* const* d_in, const int* in_sizes, int n_in,
                              void* d_out, int out_size, void* d_ws, size_t ws_size,
                              hipStream_t stream) {
    const float* x = (const float*)d_in[0];   // [B,4] fp32
    const float* w = (const float*)d_in[1];   // [5,4,3] fp32
    float* out = (float*)d_out;               // [B,4] fp32
    const int b = in_sizes[0] / N_WIRES;
    const int block = 256;
    const int grid = b / block;
    qlayer_kernel<<<grid, block, 0, stream>>>(x, w, out);
}

// Round 2
// 80.215 us; speedup vs baseline: 1.2997x; 1.2997x over previous
//
#include <hip/hip_runtime.h>
#include <math.h>

#define N_LAYERS 5
#define NG 20

// ---------------------------------------------------------------------------
// Pre-kernel: compose the 20 shared U3 gates + ring CNOTs into one 16x16
// complex unitary W, stored interleaved (re,im) in d_ws: W[(j*16+k)*2 + {0,1}]
// = <j| U |k>. One wave; thread k (k<16) propagates basis column e_k.
// ---------------------------------------------------------------------------
__global__ __launch_bounds__(64) void compose_W(const float* __restrict__ w,
                                                float* __restrict__ W) {
    __shared__ float g[NG][8];
    const int t = threadIdx.x;
    if (t < NG) {
        float th = w[t * 3 + 0], ph = w[t * 3 + 1], la = w[t * 3 + 2];
        float st, ct, sl, cl, sp, cp, spl, cpl;
        sincosf(th * 0.5f, &st, &ct);
        sincosf(la, &sl, &cl);
        sincosf(ph, &sp, &cp);
        sincosf(ph + la, &spl, &cpl);
        g[t][0] = ct;        g[t][1] = 0.0f;
        g[t][2] = -cl * st;  g[t][3] = -sl * st;
        g[t][4] = cp * st;   g[t][5] = sp * st;
        g[t][6] = cpl * ct;  g[t][7] = spl * ct;
    }
    __syncthreads();
    if (t >= 16) return;

    float ar[16], ai[16];
#pragma unroll
    for (int i = 0; i < 16; i++) { ar[i] = 0.0f; ai[i] = 0.0f; }
    ar[t] = 1.0f;

#pragma unroll
    for (int l = 0; l < N_LAYERS; l++) {
#pragma unroll
        for (int wi = 0; wi < 4; wi++) {
            const float* gm = g[l * 4 + wi];
            const float m00r = gm[0];
            const float m01r = gm[2], m01i = gm[3];
            const float m10r = gm[4], m10i = gm[5];
            const float m11r = gm[6], m11i = gm[7];
            const int stride = 8 >> wi;
#pragma unroll
            for (int base = 0; base < 16; base++) {
                if (base & stride) continue;
                const int i1 = base + stride;
                const float s0r = ar[base], s0i = ai[base];
                const float s1r = ar[i1],   s1i = ai[i1];
                ar[base] = m00r * s0r + m01r * s1r - m01i * s1i;
                ai[base] = m00r * s0i + m01r * s1i + m01i * s1r;
                ar[i1]   = m10r * s0r - m10i * s0i + m11r * s1r - m11i * s1i;
                ai[i1]   = m10r * s0i + m10i * s0r + m11r * s1i + m11i * s1r;
            }
        }
        // ring CNOTs (0,1)(1,2)(2,3)(3,0): compile-time register swaps
        const int ringc[4] = {0, 1, 2, 3};
        const int ringt[4] = {1, 2, 3, 0};
#pragma unroll
        for (int e = 0; e < 4; e++) {
            const int cm = 8 >> ringc[e];
            const int tm = 8 >> ringt[e];
#pragma unroll
            for (int idx = 0; idx < 16; idx++) {
                if ((idx & cm) && !(idx & tm)) {
                    const int j = idx | tm;
                    float tr = ar[idx]; ar[idx] = ar[j]; ar[j] = tr;
                    float ti = ai[idx]; ai[idx] = ai[j]; ai[j] = ti;
                }
            }
        }
    }
#pragma unroll
    for (int j = 0; j < 16; j++) {
        W[(j * 16 + t) * 2 + 0] = ar[j];
        W[(j * 16 + t) * 2 + 1] = ai[j];
    }
}

// ---------------------------------------------------------------------------
// Main kernel: per sample, build psi0 = v0 (x) v1 (x) v2 (x) v3 from native
// sincos, then psi = W * psi0 (W via uniform s_loads -> SGPR operands),
// probs, butterfly +/- reduction to <Z_i>.
// ---------------------------------------------------------------------------
__global__ __launch_bounds__(256) void qmain(const float* __restrict__ x,
                                             const float* __restrict__ W,
                                             float* __restrict__ out) {
    const int b = blockIdx.x * 256 + threadIdx.x;
    const float4 xv = ((const float4*)x)[b];
    const float xs[4] = {xv.x, xv.y, xv.z, xv.w};

    // encoding columns: [cos(x/2), e^{ix} sin(x/2)]
    float vr[4][2], vi[4][2];
#pragma unroll
    for (int i = 0; i < 4; i++) {
        const float st = __sinf(xs[i] * 0.5f);
        const float ct = __cosf(xs[i] * 0.5f);
        const float sx = __sinf(xs[i]);
        const float cx = __cosf(xs[i]);
        vr[i][0] = ct;      vi[i][0] = 0.0f;
        vr[i][1] = cx * st; vi[i][1] = sx * st;
    }

    // tensor product -> 16 complex amps (wire0 = bit3)
    float w01r[4], w01i[4], w23r[4], w23i[4];
#pragma unroll
    for (int a = 0; a < 2; a++) {
#pragma unroll
        for (int c = 0; c < 2; c++) {
            w01r[a * 2 + c] = vr[0][a] * vr[1][c] - vi[0][a] * vi[1][c];
            w01i[a * 2 + c] = vr[0][a] * vi[1][c] + vi[0][a] * vr[1][c];
            w23r[a * 2 + c] = vr[2][a] * vr[3][c] - vi[2][a] * vi[3][c];
            w23i[a * 2 + c] = vr[2][a] * vi[3][c] + vi[2][a] * vr[3][c];
        }
    }
    float sr[16], si[16];
#pragma unroll
    for (int hi = 0; hi < 4; hi++) {
#pragma unroll
        for (int lo = 0; lo < 4; lo++) {
            sr[hi * 4 + lo] = w01r[hi] * w23r[lo] - w01i[hi] * w23i[lo];
            si[hi * 4 + lo] = w01r[hi] * w23i[lo] + w01i[hi] * w23r[lo];
        }
    }

    // psi = W * psi0 ; p_j = |psi_j|^2. W indices are compile-time constants
    // -> uniform address -> scalar loads; FMAs take the gate as SGPR operand.
    float p[16];
#pragma unroll
    for (int j = 0; j < 16; j++) {
        float prr = 0.0f, pii = 0.0f;
#pragma unroll
        for (int k = 0; k < 16; k++) {
            const float wr = W[(j * 16 + k) * 2 + 0];
            const float wv = W[(j * 16 + k) * 2 + 1];
            prr = fmaf(wr, sr[k], prr);
            prr = fmaf(-wv, si[k], prr);
            pii = fmaf(wr, si[k], pii);
            pii = fmaf(wv, sr[k], pii);
        }
        p[j] = prr * prr + pii * pii;
    }

    // butterfly signed reduction: bit0=wire3 ... bit3=wire0
    const float a0 = p[0] + p[1],   a1 = p[2] + p[3],   a2 = p[4] + p[5],   a3 = p[6] + p[7];
    const float a4 = p[8] + p[9],   a5 = p[10] + p[11], a6 = p[12] + p[13], a7 = p[14] + p[15];
    const float z3 = (p[0] - p[1]) + (p[2] - p[3]) + (p[4] - p[5]) + (p[6] - p[7])
                   + (p[8] - p[9]) + (p[10] - p[11]) + (p[12] - p[13]) + (p[14] - p[15]);
    const float b0 = a0 + a1, b1 = a2 + a3, b2 = a4 + a5, b3 = a6 + a7;
    const float z2 = (a0 - a1) + (a2 - a3) + (a4 - a5) + (a6 - a7);
    const float c0 = b0 + b1, c1 = b2 + b3;
    const float z1 = (b0 - b1) + (b2 - b3);
    const float z0 = c0 - c1;

    ((float4*)out)[b] = make_float4(z0, z1, z2, z3);
}

extern "C" void kernel_launch(void* const* d_in, const int* in_sizes, int n_in,
                              void* d_out, int out_size, void* d_ws, size_t ws_size,
                              hipStream_t stream) {
    const float* x = (const float*)d_in[0];   // [B,4] fp32
    const float* w = (const float*)d_in[1];   // [5,4,3] fp32
    float* out = (float*)d_out;               // [B,4] fp32
    float* W = (float*)d_ws;                  // 16*16*2 floats = 2 KB
    const int b = in_sizes[0] / 4;

    compose_W<<<1, 64, 0, stream>>>(w, W);
    qmain<<<b / 256, 256, 0, stream>>>(x, W, out);
}